// Round 1
// baseline (317.679 us; speedup 1.0000x reference)
//
#include <hip/hip_runtime.h>
#include <math.h>

// ---------------------------------------------------------------------------
// Llama attention block, MI355X bf16-MFMA implementation (round 6).
//   prep: fused X-cast + all W transposes (one launch).
//   GEMM1: 256x256 8-phase counted-vmcnt template (T2+T3+T4+T5) + fused
//          RoPE/scale/pack epilogue.  vmcnt(6) steady state, never drained
//          to 0 in the main loop; half-tile ring inside 2 LDS buffers.
//   Flash v3: 2-wave blocks, 32 q-rows per strip per wave.
// ---------------------------------------------------------------------------

typedef float f32x4 __attribute__((ext_vector_type(4)));
typedef short s16x8 __attribute__((ext_vector_type(8)));
typedef unsigned short u16x4 __attribute__((ext_vector_type(4)));

__device__ __forceinline__ unsigned short f2bf(float x) {
    union { float f; unsigned int u; } v; v.f = x;
    unsigned int r = v.u + 0x7FFF + ((v.u >> 16) & 1);   // RNE
    return (unsigned short)(r >> 16);
}

// --------------------- prep: cast X + transpose-cast W ---------------------
// blocks [0, 8192): cast X (1024 f32 each). blocks [8192, 18432): W transpose.
__global__ __launch_bounds__(256) void prep(
    const float* __restrict__ X, const float* __restrict__ Wq,
    const float* __restrict__ Wk, const float* __restrict__ Wv,
    const float* __restrict__ Wo,
    unsigned short* __restrict__ Xb, unsigned short* __restrict__ Wqkvt,
    unsigned short* __restrict__ Wot) {
    const int bid = blockIdx.x;
    if (bid < 8192) {                                // ---- cast X -> bf16
        size_t i = (size_t)bid * 256 + threadIdx.x;
        f32x4 v = *(const f32x4*)&X[i * 4];
        u16x4 r;
        r[0] = f2bf(v[0]); r[1] = f2bf(v[1]); r[2] = f2bf(v[2]); r[3] = f2bf(v[3]);
        *(u16x4*)&Xb[i * 4] = r;
        return;
    }
    __shared__ float t[32][33];
    const int tb = bid - 8192;                       // 0..10239
    const int kbi = tb / 160, bx = tb - kbi * 160;
    const float* W; unsigned short* Out; int N, n0, nb;
    if (bx < 64)      { W = Wq; Out = Wqkvt; N = 2048; n0 = 0;    nb = bx; }
    else if (bx < 80) { W = Wk; Out = Wqkvt; N = 512;  n0 = 2048; nb = bx - 64; }
    else if (bx < 96) { W = Wv; Out = Wqkvt; N = 512;  n0 = 2560; nb = bx - 80; }
    else              { W = Wo; Out = Wot;   N = 2048; n0 = 0;    nb = bx - 96; }
    int kb = kbi * 32; nb *= 32;
    int tx = threadIdx.x & 31, ty = threadIdx.x >> 5;
#pragma unroll
    for (int i = 0; i < 4; ++i)
        t[ty + i * 8][tx] = W[(size_t)(kb + ty + i * 8) * N + nb + tx];
    __syncthreads();
#pragma unroll
    for (int i = 0; i < 4; ++i)
        Out[(size_t)(n0 + nb + ty + i * 8) * 2048 + kb + tx] = f2bf(t[tx][ty + i * 8]);
}

// --------------- fused QKV GEMM + RoPE + pack (GEMM1) ----------------------
// 256x256 tile, BK=64, 8 waves (2Mx4N), per-wave 128x64 output.
// 8-phase (4 phases/K-tile) schedule, counted vmcnt(6), setprio around MFMA.
__global__ __launch_bounds__(512, 2) void gemm_qkv_rope(
    const unsigned short* __restrict__ A, const unsigned short* __restrict__ Bt,
    const int* __restrict__ pos,
    unsigned short* __restrict__ Qb, unsigned short* __restrict__ Kb,
    unsigned short* __restrict__ Vb) {
    const int K = 2048;
    const int NKT = 32;                              // K / 64
    __shared__ unsigned short As[2][256 * 64];       // 64 KB
    __shared__ unsigned short Bs[2][256 * 64];       // 64 KB
    const int tid = threadIdx.x;
    const int wave = tid >> 6, lane = tid & 63;
    const int col = lane & 15, quad = lane >> 4;
    const int m0 = blockIdx.y * 256, n0 = blockIdx.x * 256;
    const int wm = (wave >> 2) * 128, wn = (wave & 3) * 64;

    // staging lanes: 8 rows x 8 chunks per wave-load; global chunk pre-swizzled
    const int lrow = lane >> 3;
    const int gch = (lane & 7) ^ lrow;
    const unsigned short* Ag = A + (size_t)(m0 + lrow) * K + gch * 8;
    const unsigned short* Bg = Bt + (size_t)(n0 + lrow) * K + gch * 8;
    const int rbA0 = wave * 8;                            // + h*64 + l*128
    const int rbB0 = ((wave >> 2) << 6) + (wave & 3) * 8; // + h*32 + l*128

    // A halves: early = rows {0-63,128-191} (mi0-3), late = {64-127,192-255}
    // B halves: early = rows {0-31,64-95,128-159,192-223} (ni0-1), late = +32
#define STAGE_A(buf, h, kt)                                                    \
    {                                                                          \
        _Pragma("unroll")                                                      \
        for (int l = 0; l < 2; ++l) {                                          \
            const int rb = (h) * 64 + l * 128 + rbA0;                          \
            __builtin_amdgcn_global_load_lds(                                  \
                (const __attribute__((address_space(1))) void*)(Ag + (size_t)rb * K + (size_t)(kt) * 64), \
                (__attribute__((address_space(3))) void*)(&As[buf][rb * 64]),  \
                16, 0, 0);                                                     \
        }                                                                      \
    }
#define STAGE_B(buf, h, kt)                                                    \
    {                                                                          \
        _Pragma("unroll")                                                      \
        for (int l = 0; l < 2; ++l) {                                          \
            const int rb = (h) * 32 + l * 128 + rbB0;                          \
            __builtin_amdgcn_global_load_lds(                                  \
                (const __attribute__((address_space(1))) void*)(Bg + (size_t)rb * K + (size_t)(kt) * 64), \
                (__attribute__((address_space(3))) void*)(&Bs[buf][rb * 64]),  \
                16, 0, 0);                                                     \
        }                                                                      \
    }
#define RD_A(buf, mi, ks)                                                      \
    (*(const s16x8*)&As[buf][(wm + (mi) * 16 + col) * 64 +                     \
                             ((((ks) << 2) + quad) ^ (col & 7)) * 8])
#define RD_B(buf, ni, ks)                                                      \
    (*(const s16x8*)&Bs[buf][(wn + (ni) * 16 + col) * 64 +                     \
                             ((((ks) << 2) + quad) ^ (col & 7)) * 8])

    s16x8 a[4][2], bl[2][2], bh[2][2];
    f32x4 acc[8][4] = {};

    // ---- prologue: tile0 fully, tile1 3/4; vmcnt(6) => tile0 landed -------
    STAGE_A(0, 0, 0); STAGE_B(0, 0, 0); STAGE_B(0, 1, 0); STAGE_A(0, 1, 0);
    STAGE_A(1, 0, 1); STAGE_B(1, 0, 1); STAGE_B(1, 1, 1);
    asm volatile("s_waitcnt vmcnt(6)" ::: "memory");
    __builtin_amdgcn_s_barrier();

    for (int t = 0; t < NKT; ++t) {
        const int p = t & 1;
        // ---------------- phase 0: A-early + B-early, MFMA m0-3 x n0-1 -----
#pragma unroll
        for (int mi = 0; mi < 4; ++mi) {
            a[mi][0] = RD_A(p, mi, 0);
            a[mi][1] = RD_A(p, mi, 1);
        }
#pragma unroll
        for (int ni = 0; ni < 2; ++ni) {
            bl[ni][0] = RD_B(p, ni, 0);
            bl[ni][1] = RD_B(p, ni, 1);
        }
        if (t + 1 < NKT) STAGE_A(p ^ 1, 1, t + 1);   // A-late(t+1)
        __builtin_amdgcn_s_barrier();
        asm volatile("s_waitcnt lgkmcnt(0)" ::: "memory");
        __builtin_amdgcn_s_setprio(1);
#pragma unroll
        for (int mi = 0; mi < 4; ++mi)
#pragma unroll
            for (int ni = 0; ni < 2; ++ni) {
                acc[mi][ni] = __builtin_amdgcn_mfma_f32_16x16x32_bf16(a[mi][0], bl[ni][0], acc[mi][ni], 0, 0, 0);
                acc[mi][ni] = __builtin_amdgcn_mfma_f32_16x16x32_bf16(a[mi][1], bl[ni][1], acc[mi][ni], 0, 0, 0);
            }
        __builtin_amdgcn_s_setprio(0);
        __builtin_amdgcn_s_barrier();
        // ---------------- phase 1: B-late, MFMA m0-3 x n2-3 ---------------
#pragma unroll
        for (int ni = 0; ni < 2; ++ni) {
            bh[ni][0] = RD_B(p, 2 + ni, 0);
            bh[ni][1] = RD_B(p, 2 + ni, 1);
        }
        if (t + 2 < NKT) STAGE_A(p, 0, t + 2);       // A-early(t+2)
        __builtin_amdgcn_s_barrier();
        asm volatile("s_waitcnt lgkmcnt(0)" ::: "memory");
        __builtin_amdgcn_s_setprio(1);
#pragma unroll
        for (int mi = 0; mi < 4; ++mi)
#pragma unroll
            for (int ni = 0; ni < 2; ++ni) {
                acc[mi][2 + ni] = __builtin_amdgcn_mfma_f32_16x16x32_bf16(a[mi][0], bh[ni][0], acc[mi][2 + ni], 0, 0, 0);
                acc[mi][2 + ni] = __builtin_amdgcn_mfma_f32_16x16x32_bf16(a[mi][1], bh[ni][1], acc[mi][2 + ni], 0, 0, 0);
            }
        __builtin_amdgcn_s_setprio(0);
        __builtin_amdgcn_s_barrier();
        // ---------------- phase 2: A-late, MFMA m4-7 x n2-3 ---------------
#pragma unroll
        for (int mi = 0; mi < 4; ++mi) {
            a[mi][0] = RD_A(p, 4 + mi, 0);
            a[mi][1] = RD_A(p, 4 + mi, 1);
        }
        if (t + 2 < NKT) STAGE_B(p, 0, t + 2);       // B-early(t+2)
        __builtin_amdgcn_s_barrier();
        asm volatile("s_waitcnt lgkmcnt(0)" ::: "memory");
        __builtin_amdgcn_s_setprio(1);
#pragma unroll
        for (int mi = 0; mi < 4; ++mi)
#pragma unroll
            for (int ni = 0; ni < 2; ++ni) {
                acc[4 + mi][2 + ni] = __builtin_amdgcn_mfma_f32_16x16x32_bf16(a[mi][0], bh[ni][0], acc[4 + mi][2 + ni], 0, 0, 0);
                acc[4 + mi][2 + ni] = __builtin_amdgcn_mfma_f32_16x16x32_bf16(a[mi][1], bh[ni][1], acc[4 + mi][2 + ni], 0, 0, 0);
            }
        __builtin_amdgcn_s_setprio(0);
        __builtin_amdgcn_s_barrier();
        // ---------------- phase 3: MFMA m4-7 x n0-1; tile boundary --------
        if (t + 2 < NKT) STAGE_B(p, 1, t + 2);       // B-late(t+2)
        if (t + 2 < NKT) {                           // 3 half-tiles in flight
            asm volatile("s_waitcnt vmcnt(6)" ::: "memory");
        } else {                                     // epilogue drain
            asm volatile("s_waitcnt vmcnt(0)" ::: "memory");
        }
        __builtin_amdgcn_s_barrier();
        __builtin_amdgcn_s_setprio(1);
#pragma unroll
        for (int mi = 0; mi < 4; ++mi)
#pragma unroll
            for (int ni = 0; ni < 2; ++ni) {
                acc[4 + mi][ni] = __builtin_amdgcn_mfma_f32_16x16x32_bf16(a[mi][0], bl[ni][0], acc[4 + mi][ni], 0, 0, 0);
                acc[4 + mi][ni] = __builtin_amdgcn_mfma_f32_16x16x32_bf16(a[mi][1], bl[ni][1], acc[4 + mi][ni], 0, 0, 0);
            }
        __builtin_amdgcn_s_setprio(0);
        __builtin_amdgcn_s_barrier();
    }
#undef STAGE_A
#undef STAGE_B
#undef RD_A
#undef RD_B

    // ---- epilogue: per-wave 64-col block == one head ----------------------
    const int cb = n0 + wn;
    if (cb >= 2560) {                                // V: straight bf16 store
        const int hd = (cb - 2560) >> 6;
#pragma unroll
        for (int mi = 0; mi < 8; ++mi)
#pragma unroll
            for (int r = 0; r < 4; ++r) {
                int m = m0 + wm + mi * 16 + quad * 4 + r;
                int b = m >> 11, s = m & 2047;
                size_t rb = ((size_t)(b * 8 + hd) * 2048 + s) * 64;
#pragma unroll
                for (int ni = 0; ni < 4; ++ni)
                    Vb[rb + ni * 16 + col] = f2bf(acc[mi][ni][r]);
            }
    } else {                                         // Q or K: RoPE
        const int isQ = (cb < 2048);
        const int hd = isQ ? (cb >> 6) : ((cb - 2048) >> 6);
        const int nh = isQ ? 32 : 8;
        const float scale = isQ ? 0.125f : 1.0f;
        unsigned short* Out = isQ ? Qb : Kb;
        const float NEG_LN_TH_32 = -0.28782313662425575f;
        const float inv0 = __expf((float)col * NEG_LN_TH_32);
        const float inv1 = __expf((float)(col + 16) * NEG_LN_TH_32);
#pragma unroll
        for (int mi = 0; mi < 8; ++mi)
#pragma unroll
            for (int r = 0; r < 4; ++r) {
                int m = m0 + wm + mi * 16 + quad * 4 + r;
                int b = m >> 11, s = m & 2047;
                float p = (float)pos[m];
                float sn0, cs0, sn1, cs1;
                __sincosf(p * inv0, &sn0, &cs0);
                __sincosf(p * inv1, &sn1, &cs1);
                float a0 = acc[mi][0][r], a1 = acc[mi][1][r];
                float b0 = acc[mi][2][r], b1 = acc[mi][3][r];
                size_t rb = ((size_t)(b * nh + hd) * 2048 + s) * 64;
                Out[rb + col]      = f2bf((a0 * cs0 - b0 * sn0) * scale);
                Out[rb + col + 16] = f2bf((a1 * cs1 - b1 * sn1) * scale);
                Out[rb + col + 32] = f2bf((b0 * cs0 + a0 * sn0) * scale);
                Out[rb + col + 48] = f2bf((b1 * cs1 + a1 * sn1) * scale);
            }
    }
}

// ------------------------------ bf16 GEMM (GEMM2) --------------------------
__global__ __launch_bounds__(256) void gemm_bf16_nt(
    const unsigned short* __restrict__ A, const unsigned short* __restrict__ Bt,
    float* __restrict__ C, int K, int ldc) {
    __shared__ unsigned short As[128 * 64];
    __shared__ unsigned short Bs[128 * 64];
    const int tid = threadIdx.x;
    const int wave = tid >> 6, lane = tid & 63;
    const int col = lane & 15, quad = lane >> 4;
    const int m0 = blockIdx.y * 128, n0 = blockIdx.x * 128;
    const int wm = (wave >> 1) * 64, wn = (wave & 1) * 64;

    const int lrow = lane >> 3;
    const int gch = (lane & 7) ^ lrow;
    const unsigned short* Ag = A + (size_t)(m0 + wave * 32 + lrow) * K + gch * 8;
    const unsigned short* Bg = Bt + (size_t)(n0 + wave * 32 + lrow) * K + gch * 8;
    unsigned short* AsW = As + wave * 2048;
    unsigned short* BsW = Bs + wave * 2048;

    f32x4 acc[4][4] = {};

    for (int k0 = 0; k0 < K; k0 += 64) {
#pragma unroll
        for (int i = 0; i < 4; ++i) {
            __builtin_amdgcn_global_load_lds(
                (const __attribute__((address_space(1))) void*)(Ag + (size_t)i * 8 * K + k0),
                (__attribute__((address_space(3))) void*)(AsW + i * 512), 16, 0, 0);
            __builtin_amdgcn_global_load_lds(
                (const __attribute__((address_space(1))) void*)(Bg + (size_t)i * 8 * K + k0),
                (__attribute__((address_space(3))) void*)(BsW + i * 512), 16, 0, 0);
        }
        __syncthreads();
#pragma unroll
        for (int ks = 0; ks < 2; ++ks) {
            const int slot = ((ks << 2) + quad) ^ (col & 7);
            s16x8 af[4], bf[4];
#pragma unroll
            for (int mi = 0; mi < 4; ++mi)
                af[mi] = *(const s16x8*)&As[(wm + mi * 16 + col) * 64 + slot * 8];
#pragma unroll
            for (int ni = 0; ni < 4; ++ni)
                bf[ni] = *(const s16x8*)&Bs[(wn + ni * 16 + col) * 64 + slot * 8];
#pragma unroll
            for (int mi = 0; mi < 4; ++mi)
#pragma unroll
                for (int ni = 0; ni < 4; ++ni)
                    acc[mi][ni] = __builtin_amdgcn_mfma_f32_16x16x32_bf16(
                        af[mi], bf[ni], acc[mi][ni], 0, 0, 0);
        }
        __syncthreads();
    }
#pragma unroll
    for (int mi = 0; mi < 4; ++mi)
#pragma unroll
        for (int ni = 0; ni < 4; ++ni)
#pragma unroll
            for (int r = 0; r < 4; ++r) {
                int m = m0 + wm + mi * 16 + quad * 4 + r;
                int n = n0 + wn + ni * 16 + col;
                C[(size_t)m * ldc + n] = acc[mi][ni][r];
            }
}

// ------------------------------ V transpose --------------------------------
__global__ __launch_bounds__(256) void transpose_v(
    const unsigned short* __restrict__ Vb, unsigned short* __restrict__ Vt) {
    __shared__ unsigned short t[64 * 66];
    const int bh = blockIdx.x >> 5, st = blockIdx.x & 31;
    const unsigned short* src = Vb + ((size_t)bh * 2048 + st * 64) * 64;
    unsigned short* dst = Vt + (size_t)bh * 64 * 2048 + st * 64;
    const int r = threadIdx.x >> 2, c = (threadIdx.x & 3) * 16;
    s16x8 v0 = *(const s16x8*)&src[r * 64 + c];
    s16x8 v1 = *(const s16x8*)&src[r * 64 + c + 8];
    unsigned* tw = (unsigned*)&t[r * 66 + c];
#pragma unroll
    for (int q2 = 0; q2 < 4; ++q2) tw[q2] = ((unsigned*)&v0)[q2];
#pragma unroll
    for (int q2 = 0; q2 < 4; ++q2) tw[4 + q2] = ((unsigned*)&v1)[q2];
    __syncthreads();
    const int d = threadIdx.x >> 2, sc2 = (threadIdx.x & 3) * 16;
    unsigned short outv[16];
#pragma unroll
    for (int jj = 0; jj < 16; ++jj) outv[jj] = t[(sc2 + jj) * 66 + d];
    *(s16x8*)&dst[(size_t)d * 2048 + sc2] = *(s16x8*)&outv[0];
    *(s16x8*)&dst[(size_t)d * 2048 + sc2 + 8] = *(s16x8*)&outv[8];
}

// ---------------------------- flash attention v3 ---------------------------
// 1024 blocks x 128 threads (2 waves). Block: strips A=(31-j)*64, B=j*64;
// wave w owns q rows [strip + w*32, +32) of EACH strip (2 q-frags per strip).
__global__ __launch_bounds__(128, 2) void flash_attn(
    const unsigned short* __restrict__ Qb, const unsigned short* __restrict__ Kb,
    const unsigned short* __restrict__ Vt, unsigned short* __restrict__ Ob) {
    __shared__ unsigned short Ks[64 * 64];           // [kv][d]   xor-chunked
    __shared__ unsigned short Vs[64 * 64];           // [d][kv]   xor-chunked
    __shared__ unsigned short PsA[2][32 * 64];       // per-wave P^T->A-layout
    __shared__ unsigned short PsB[2][32 * 64];

    const int tid = threadIdx.x;
    const int wave = tid >> 6, lane = tid & 63;
    const int col = lane & 15, quad = lane >> 4;

    const int id = blockIdx.x;                       // 0..1023
    const int j = ((id & 15) + ((id >> 8) << 2)) & 15;
    const int bh = id >> 4;
    const int b = bh >> 5, h = bh & 31, kvh = h >> 2;
    const int qA0 = (31 - j) * 64, qB0 = j * 64;
    const int qwA = qA0 + wave * 32, qwB = qB0 + wave * 32;

    const unsigned short* Qg  = Qb + ((size_t)(b * 32 + h) * 2048) * 64;
    const unsigned short* Kgb = Kb + ((size_t)(b * 8 + kvh) * 2048) * 64;
    const unsigned short* Vgb = Vt + ((size_t)(b * 8 + kvh) * 64) * 2048;

    const int r8 = lane >> 3, g = (lane & 7) ^ r8;
    const unsigned short* KgL = Kgb + (size_t)(wave * 32 + r8) * 64 + g * 8;
    const unsigned short* VgL = Vgb + (size_t)(wave * 32 + r8) * 2048 + g * 8;
    unsigned short* KsW = Ks + wave * 32 * 64;
    unsigned short* VsW = Vs + wave * 32 * 64;

    const s16x8 onesf = {16256, 16256, 16256, 16256, 16256, 16256, 16256, 16256};

    s16x8 qfA[2][2], qfB[2][2];                      // [q-chunk][ks]
#pragma unroll
    for (int qc = 0; qc < 2; ++qc)
#pragma unroll
        for (int ks = 0; ks < 2; ++ks) {
            qfA[qc][ks] = *(const s16x8*)&Qg[(size_t)(qwA + qc * 16 + col) * 64 + ks * 32 + quad * 8];
            qfB[qc][ks] = *(const s16x8*)&Qg[(size_t)(qwB + qc * 16 + col) * 64 + ks * 32 + quad * 8];
        }

    f32x4 aoA[2][4] = {}, aoB[2][4] = {};            // [q-chunk][d-chunk]
    f32x4 alA[2] = {}, alB[2] = {};

    for (int kv0 = 0; kv0 <= qA0; kv0 += 64) {
#pragma unroll
        for (int i = 0; i < 4; ++i) {                // stage K,V (8 KB each)
            __builtin_amdgcn_global_load_lds(
                (const __attribute__((address_space(1))) void*)(KgL + (size_t)(kv0 + i * 8) * 64),
                (__attribute__((address_space(3))) void*)(KsW + i * 512), 16, 0, 0);
            __builtin_amdgcn_global_load_lds(
                (const __attribute__((address_space(1))) void*)(VgL + kv0 + (size_t)i * 8 * 2048),
                (__attribute__((address_space(3))) void*)(VsW + i * 512), 16, 0, 0);
        }
        __syncthreads();
        const bool doB = (kv0 <= qB0);
        // ---- QK^T (S^T), exp, pack --------------------------------------
#pragma unroll
        for (int mi = 0; mi < 4; ++mi) {
            const int s0 = quad ^ (col & 7);
            const int s1 = (4 + quad) ^ (col & 7);
            s16x8 kf0 = *(const s16x8*)&Ks[(mi * 16 + col) * 64 + s0 * 8];
            s16x8 kf1 = *(const s16x8*)&Ks[(mi * 16 + col) * 64 + s1 * 8];
            const int chl = (mi * 2 + (quad >> 1)) ^ (col & 7);
#pragma unroll
            for (int qc = 0; qc < 2; ++qc) {
                f32x4 sc = {};
                sc = __builtin_amdgcn_mfma_f32_16x16x32_bf16(kf0, qfA[qc][0], sc, 0, 0, 0);
                sc = __builtin_amdgcn_mfma_f32_16x16x32_bf16(kf1, qfA[qc][1], sc, 0, 0, 0);
                if (kv0 == qA0) {                    // diagonal tile mask
                    int kvb = kv0 + mi * 16 + quad * 4, q = qwA + qc * 16 + col;
#pragma unroll
                    for (int r = 0; r < 4; ++r)
                        if (kvb + r > q) sc[r] = -1e30f;
                }
                unsigned eb[4];
#pragma unroll
                for (int r = 0; r < 4; ++r) eb[r] = __float_as_uint(__expf(sc[r]));
                uint2 pk;
                pk.x = __builtin_amdgcn_perm(eb[1], eb[0], 0x07060302u);
                pk.y = __builtin_amdgcn_perm(eb[3], eb[2], 0x07060302u);
                *(uint2*)&PsA[wave][(qc * 16 + col) * 64 + chl * 8 + (quad & 1) * 4] = pk;
            }
            if (doB) {
#pragma unroll
                for (int qc = 0; qc < 2; ++qc) {
                    f32x4 sc = {};
                    sc = __builtin_amdgcn_mfma_f32_16x16x32_bf16(kf0, qfB[qc][0], sc, 0, 0, 0);
                    sc = __builtin_amdgcn_mfma_f32_16x16x32_bf16(kf1, qfB[qc][1], sc, 0, 0, 0);
                    if (kv0 == qB0) {
                        int kvb = kv0 + mi * 16 + quad * 4, q = qwB + qc * 16 + col;
#pragma unroll
                        for (int r = 0; r < 4; ++r)
                            if (kvb + r > q) sc[r] = -1e30f;
                    }
                    unsigned eb[4];
#pragma unroll
                    for (int r = 0; r < 4; ++r) eb[r] = __float_as_uint(__expf(sc[r]));
                    uint2 pk;
                    pk.x = __builtin_amdgcn_perm(eb[1], eb[0], 0x07060302u);
                    pk.y = __builtin_amdgcn_perm(eb[3], eb[2], 0x07060302u);
                    *(uint2*)&PsB[wave][(qc * 16 + col) * 64 + chl * 8 + (quad & 1) * 4] = pk;
                }
            }
        }
        asm volatile("s_waitcnt lgkmcnt(0)" ::: "memory");
        // ---- O += P @ V ; l += P @ 1 (vf shared across 4 q-frags) --------
#pragma unroll
        for (int ks = 0; ks < 2; ++ks) {
            const int slot = ((ks << 2) + quad) ^ (col & 7);
            s16x8 vf[4];
#pragma unroll
            for (int di = 0; di < 4; ++di)
                vf[di] = *(const s16x8*)&Vs[(di * 16 + col) * 64 + slot * 8];
#pragma unroll
            for (int qc = 0; qc < 2; ++qc) {
                s16x8 pfA = *(const s16x8*)&PsA[wave][(qc * 16 + col) * 64 + slot * 8];
                alA[qc] = __builtin_amdgcn_mfma_f32_16x16x32_bf16(pfA, onesf, alA[qc], 0, 0, 0);
#pragma unroll
                for (int di = 0; di < 4; ++di)
                    aoA[qc][di] = __builtin_amdgcn_mfma_f32_16x16x32_bf16(pfA, vf[di], aoA[qc][di], 0, 0, 0);
            }
            if (doB) {
#pragma unroll
                for (int qc = 0; qc < 2; ++qc) {
                    s16x8 pfB = *(const s16x8*)&PsB[wave][(qc * 16 + col) * 64 + slot * 8];
                    alB[qc] = __builtin_amdgcn_mfma_f32_16x16x32_bf16(pfB, onesf, alB[qc], 0, 0, 0);
#pragma unroll
                    for (int di = 0; di < 4; ++di)
                        aoB[qc][di] = __builtin_amdgcn_mfma_f32_16x16x32_bf16(pfB, vf[di], aoB[qc][di], 0, 0, 0);
                }
            }
        }
        __syncthreads();
    }

    // ---- epilogue ---------------------------------------------------------
#pragma unroll
    for (int qc = 0; qc < 2; ++qc)
#pragma unroll
        for (int r = 0; r < 4; ++r) {
            {
                int qg = qwA + qc * 16 + quad * 4 + r;
                float inv = 1.f / alA[qc][r];
                size_t base = ((size_t)b * 2048 + qg) * 2048 + h * 64;
#pragma unroll
                for (int di = 0; di < 4; ++di)
                    Ob[base + di * 16 + col] = f2bf(aoA[qc][di][r] * inv);
            }
            {
                int qg = qwB + qc * 16 + quad * 4 + r;
                float inv = 1.f / alB[qc][r];
                size_t base = ((size_t)b * 2048 + qg) * 2048 + h * 64;
#pragma unroll
                for (int di = 0; di < 4; ++di)
                    Ob[base + di * 16 + col] = f2bf(aoB[qc][di][r] * inv);
            }
        }
}

// ------------------------------- launcher ----------------------------------
extern "C" void kernel_launch(void* const* d_in, const int* in_sizes, int n_in,
                              void* d_out, int out_size, void* d_ws, size_t ws_size,
                              hipStream_t stream) {
    const float* X  = (const float*)d_in[0];
    const float* Wq = (const float*)d_in[1];
    const float* Wk = (const float*)d_in[2];
    const float* Wv = (const float*)d_in[3];
    const float* Wo = (const float*)d_in[4];
    const int* pos  = (const int*)d_in[6];
    float* out = (float*)d_out;

    char* ws = (char*)d_ws;
    unsigned short* Xb    = (unsigned short*)(ws + 0);          // 16 MB (reused as Attn)
    unsigned short* Wqkvt = (unsigned short*)(ws + 16777216);   // 12 MB
    unsigned short* Wot   = (unsigned short*)(ws + 29360128);   // 8 MB
    unsigned short* Qb    = (unsigned short*)(ws + 37748736);   // 16 MB
    unsigned short* Kb    = (unsigned short*)(ws + 54525952);   // 4 MB
    unsigned short* Vb    = (unsigned short*)(ws + 58720256);   // 4 MB
    unsigned short* Vt    = (unsigned short*)(ws + 62914560);   // 4 MB
    unsigned short* Attn  = Xb;                                 // alias

    prep<<<18432, 256, 0, stream>>>(X, Wq, Wk, Wv, Wo, Xb, Wqkvt, Wot);
    gemm_qkv_rope<<<dim3(12, 16), 512, 0, stream>>>(Xb, Wqkvt, pos, Qb, Kb, Vb);
    transpose_v<<<512, 256, 0, stream>>>(Vb, Vt);
    flash_attn<<<1024, 128, 0, stream>>>(Qb, Kb, Vt, Attn);
    gemm_bf16_nt<<<dim3(16, 32), 256, 0, stream>>>(Attn, Wot, out, 2048, 2048);
}

// Round 2
// 307.641 us; speedup vs baseline: 1.0326x; 1.0326x over previous
//
#include <hip/hip_runtime.h>
#include <math.h>

// ---------------------------------------------------------------------------
// Llama attention block, MI355X bf16-MFMA implementation (round 7).
//   prep: fused X-cast + all W transposes (one launch).
//   GEMM1: 256x256 8-phase template + XCD-rect swizzle (6x4), deep stagger:
//          each half-tile staged at earliest-free phase (t+2), boundary
//          vmcnt(8) AFTER ph3 MFMA -> youngest awaited load is 5 phases old.
//   GEMM2: + XCD-rect swizzle (8x8).
//   Flash v3: 2-wave blocks, 32 q-rows per strip per wave.
// ---------------------------------------------------------------------------

typedef float f32x4 __attribute__((ext_vector_type(4)));
typedef short s16x8 __attribute__((ext_vector_type(8)));
typedef unsigned short u16x4 __attribute__((ext_vector_type(4)));

__device__ __forceinline__ unsigned short f2bf(float x) {
    union { float f; unsigned int u; } v; v.f = x;
    unsigned int r = v.u + 0x7FFF + ((v.u >> 16) & 1);   // RNE
    return (unsigned short)(r >> 16);
}

// --------------------- prep: cast X + transpose-cast W ---------------------
// blocks [0, 8192): cast X (1024 f32 each). blocks [8192, 18432): W transpose.
__global__ __launch_bounds__(256) void prep(
    const float* __restrict__ X, const float* __restrict__ Wq,
    const float* __restrict__ Wk, const float* __restrict__ Wv,
    const float* __restrict__ Wo,
    unsigned short* __restrict__ Xb, unsigned short* __restrict__ Wqkvt,
    unsigned short* __restrict__ Wot) {
    const int bid = blockIdx.x;
    if (bid < 8192) {                                // ---- cast X -> bf16
        size_t i = (size_t)bid * 256 + threadIdx.x;
        f32x4 v = *(const f32x4*)&X[i * 4];
        u16x4 r;
        r[0] = f2bf(v[0]); r[1] = f2bf(v[1]); r[2] = f2bf(v[2]); r[3] = f2bf(v[3]);
        *(u16x4*)&Xb[i * 4] = r;
        return;
    }
    __shared__ float t[32][33];
    const int tb = bid - 8192;                       // 0..10239
    const int kbi = tb / 160, bx = tb - kbi * 160;
    const float* W; unsigned short* Out; int N, n0, nb;
    if (bx < 64)      { W = Wq; Out = Wqkvt; N = 2048; n0 = 0;    nb = bx; }
    else if (bx < 80) { W = Wk; Out = Wqkvt; N = 512;  n0 = 2048; nb = bx - 64; }
    else if (bx < 96) { W = Wv; Out = Wqkvt; N = 512;  n0 = 2560; nb = bx - 80; }
    else              { W = Wo; Out = Wot;   N = 2048; n0 = 0;    nb = bx - 96; }
    int kb = kbi * 32; nb *= 32;
    int tx = threadIdx.x & 31, ty = threadIdx.x >> 5;
#pragma unroll
    for (int i = 0; i < 4; ++i)
        t[ty + i * 8][tx] = W[(size_t)(kb + ty + i * 8) * N + nb + tx];
    __syncthreads();
#pragma unroll
    for (int i = 0; i < 4; ++i)
        Out[(size_t)(n0 + nb + ty + i * 8) * 2048 + kb + tx] = f2bf(t[tx][ty + i * 8]);
}

// --------------- fused QKV GEMM + RoPE + pack (GEMM1) ----------------------
// 256x256 tile, BK=64, 8 waves (2Mx4N), per-wave 128x64 output.
// Deep-staggered 4-phase/K-tile schedule; vmcnt(8) boundary after ph3 MFMA.
__global__ __launch_bounds__(512, 2) void gemm_qkv_rope(
    const unsigned short* __restrict__ A, const unsigned short* __restrict__ Bt,
    const int* __restrict__ pos,
    unsigned short* __restrict__ Qb, unsigned short* __restrict__ Kb,
    unsigned short* __restrict__ Vb) {
    const int K = 2048;
    const int NKT = 32;                              // K / 64
    __shared__ unsigned short As[2][256 * 64];       // 64 KB
    __shared__ unsigned short Bs[2][256 * 64];       // 64 KB
    const int tid = threadIdx.x;
    const int wave = tid >> 6, lane = tid & 63;
    const int col = lane & 15, quad = lane >> 4;

    // XCD-rect swizzle: grid (12,16) -> 8 XCDs x (6x4) rectangles.
    // per-XCD unique panel = 6 B-slabs + 4 A-slabs = 10 MB (vs ~48 unswizzled).
    const int lin = blockIdx.y * 12 + blockIdx.x;
    const int xcd = lin & 7, t6 = lin >> 3;          // t6: 0..23
    const int bx = (xcd & 1) * 6 + (t6 % 6);         // 0..11
    const int by = (xcd >> 1) * 4 + (t6 / 6);        // 0..15
    const int m0 = by * 256, n0 = bx * 256;
    const int wm = (wave >> 2) * 128, wn = (wave & 3) * 64;

    // staging lanes: 8 rows x 8 chunks per wave-load; global chunk pre-swizzled
    const int lrow = lane >> 3;
    const int gch = (lane & 7) ^ lrow;
    const unsigned short* Ag = A + (size_t)(m0 + lrow) * K + gch * 8;
    const unsigned short* Bg = Bt + (size_t)(n0 + lrow) * K + gch * 8;
    const int rbA0 = wave * 8;                            // + h*64 + l*128
    const int rbB0 = ((wave >> 2) << 6) + (wave & 3) * 8; // + h*32 + l*128

    // A halves: early = rows {0-63,128-191} (mi0-3), late = {64-127,192-255}
    // B halves: early = rows {0-31,64-95,128-159,192-223} (ni0-1), late = +32
#define STAGE_A(buf, h, kt)                                                    \
    {                                                                          \
        _Pragma("unroll")                                                      \
        for (int l = 0; l < 2; ++l) {                                          \
            const int rb = (h) * 64 + l * 128 + rbA0;                          \
            __builtin_amdgcn_global_load_lds(                                  \
                (const __attribute__((address_space(1))) void*)(Ag + (size_t)rb * K + (size_t)(kt) * 64), \
                (__attribute__((address_space(3))) void*)(&As[buf][rb * 64]),  \
                16, 0, 0);                                                     \
        }                                                                      \
    }
#define STAGE_B(buf, h, kt)                                                    \
    {                                                                          \
        _Pragma("unroll")                                                      \
        for (int l = 0; l < 2; ++l) {                                          \
            const int rb = (h) * 32 + l * 128 + rbB0;                          \
            __builtin_amdgcn_global_load_lds(                                  \
                (const __attribute__((address_space(1))) void*)(Bg + (size_t)rb * K + (size_t)(kt) * 64), \
                (__attribute__((address_space(3))) void*)(&Bs[buf][rb * 64]),  \
                16, 0, 0);                                                     \
        }                                                                      \
    }
#define RD_A(buf, mi, ks)                                                      \
    (*(const s16x8*)&As[buf][(wm + (mi) * 16 + col) * 64 +                     \
                             ((((ks) << 2) + quad) ^ (col & 7)) * 8])
#define RD_B(buf, ni, ks)                                                      \
    (*(const s16x8*)&Bs[buf][(wn + (ni) * 16 + col) * 64 +                     \
                             ((((ks) << 2) + quad) ^ (col & 7)) * 8])
#define SB0 __builtin_amdgcn_sched_barrier(0)

    s16x8 a[4][2], bl[2][2], bh[2][2];
    f32x4 acc[8][4] = {};

    // ---- prologue: stage tiles 0 and 1 fully; vmcnt(8) => tile0 landed ----
    STAGE_A(0, 0, 0); STAGE_B(0, 0, 0); STAGE_B(0, 1, 0); STAGE_A(0, 1, 0);
    STAGE_A(1, 0, 1); STAGE_B(1, 0, 1); STAGE_B(1, 1, 1); STAGE_A(1, 1, 1);
    asm volatile("s_waitcnt vmcnt(8)" ::: "memory");
    __builtin_amdgcn_s_barrier();

    for (int t = 0; t < NKT; ++t) {
        const int p = t & 1;
        const bool pf = (t + 2 < NKT);
        // ---------------- phase 0: rd A-early + B-early; MFMA m0-3 x n0-1 --
#pragma unroll
        for (int mi = 0; mi < 4; ++mi) {
            a[mi][0] = RD_A(p, mi, 0);
            a[mi][1] = RD_A(p, mi, 1);
        }
#pragma unroll
        for (int ni = 0; ni < 2; ++ni) {
            bl[ni][0] = RD_B(p, ni, 0);
            bl[ni][1] = RD_B(p, ni, 1);
        }
        __builtin_amdgcn_s_barrier();
        asm volatile("s_waitcnt lgkmcnt(0)" ::: "memory");
        SB0;
        __builtin_amdgcn_s_setprio(1);
#pragma unroll
        for (int mi = 0; mi < 4; ++mi)
#pragma unroll
            for (int ni = 0; ni < 2; ++ni) {
                acc[mi][ni] = __builtin_amdgcn_mfma_f32_16x16x32_bf16(a[mi][0], bl[ni][0], acc[mi][ni], 0, 0, 0);
                acc[mi][ni] = __builtin_amdgcn_mfma_f32_16x16x32_bf16(a[mi][1], bl[ni][1], acc[mi][ni], 0, 0, 0);
            }
        __builtin_amdgcn_s_setprio(0);
        SB0;
        __builtin_amdgcn_s_barrier();
        // ---------------- phase 1: rd B-late; stage A-e,B-e(t+2); m0-3xn2-3
#pragma unroll
        for (int ni = 0; ni < 2; ++ni) {
            bh[ni][0] = RD_B(p, 2 + ni, 0);
            bh[ni][1] = RD_B(p, 2 + ni, 1);
        }
        if (pf) { STAGE_A(p, 0, t + 2); STAGE_B(p, 0, t + 2); }
        __builtin_amdgcn_s_barrier();
        asm volatile("s_waitcnt lgkmcnt(0)" ::: "memory");
        SB0;
        __builtin_amdgcn_s_setprio(1);
#pragma unroll
        for (int mi = 0; mi < 4; ++mi)
#pragma unroll
            for (int ni = 0; ni < 2; ++ni) {
                acc[mi][2 + ni] = __builtin_amdgcn_mfma_f32_16x16x32_bf16(a[mi][0], bh[ni][0], acc[mi][2 + ni], 0, 0, 0);
                acc[mi][2 + ni] = __builtin_amdgcn_mfma_f32_16x16x32_bf16(a[mi][1], bh[ni][1], acc[mi][2 + ni], 0, 0, 0);
            }
        __builtin_amdgcn_s_setprio(0);
        SB0;
        __builtin_amdgcn_s_barrier();
        // ---------------- phase 2: rd A-late; stage B-l(t+2); m4-7 x n2-3 --
#pragma unroll
        for (int mi = 0; mi < 4; ++mi) {
            a[mi][0] = RD_A(p, 4 + mi, 0);
            a[mi][1] = RD_A(p, 4 + mi, 1);
        }
        if (pf) STAGE_B(p, 1, t + 2);
        __builtin_amdgcn_s_barrier();
        asm volatile("s_waitcnt lgkmcnt(0)" ::: "memory");
        SB0;
        __builtin_amdgcn_s_setprio(1);
#pragma unroll
        for (int mi = 0; mi < 4; ++mi)
#pragma unroll
            for (int ni = 0; ni < 2; ++ni) {
                acc[4 + mi][2 + ni] = __builtin_amdgcn_mfma_f32_16x16x32_bf16(a[mi][0], bh[ni][0], acc[4 + mi][2 + ni], 0, 0, 0);
                acc[4 + mi][2 + ni] = __builtin_amdgcn_mfma_f32_16x16x32_bf16(a[mi][1], bh[ni][1], acc[4 + mi][2 + ni], 0, 0, 0);
            }
        __builtin_amdgcn_s_setprio(0);
        SB0;
        __builtin_amdgcn_s_barrier();
        // ---------------- phase 3: stage A-l(t+2); MFMA m4-7 x n0-1;
        //                  boundary vmcnt AFTER MFMA (regs only), then barrier
        if (pf) STAGE_A(p, 1, t + 2);
        __builtin_amdgcn_s_barrier();
        __builtin_amdgcn_s_setprio(1);
#pragma unroll
        for (int mi = 0; mi < 4; ++mi)
#pragma unroll
            for (int ni = 0; ni < 2; ++ni) {
                acc[4 + mi][ni] = __builtin_amdgcn_mfma_f32_16x16x32_bf16(a[mi][0], bl[ni][0], acc[4 + mi][ni], 0, 0, 0);
                acc[4 + mi][ni] = __builtin_amdgcn_mfma_f32_16x16x32_bf16(a[mi][1], bl[ni][1], acc[4 + mi][ni], 0, 0, 0);
            }
        __builtin_amdgcn_s_setprio(0);
        SB0;
        if (pf) {                                    // keep t+2's 8 loads in flight
            asm volatile("s_waitcnt vmcnt(8)" ::: "memory");
        } else {                                     // tail drain
            asm volatile("s_waitcnt vmcnt(0)" ::: "memory");
        }
        SB0;
        __builtin_amdgcn_s_barrier();
    }
#undef STAGE_A
#undef STAGE_B
#undef RD_A
#undef RD_B
#undef SB0

    // ---- epilogue: per-wave 64-col block == one head ----------------------
    const int cb = n0 + wn;
    if (cb >= 2560) {                                // V: straight bf16 store
        const int hd = (cb - 2560) >> 6;
#pragma unroll
        for (int mi = 0; mi < 8; ++mi)
#pragma unroll
            for (int r = 0; r < 4; ++r) {
                int m = m0 + wm + mi * 16 + quad * 4 + r;
                int b = m >> 11, s = m & 2047;
                size_t rb = ((size_t)(b * 8 + hd) * 2048 + s) * 64;
#pragma unroll
                for (int ni = 0; ni < 4; ++ni)
                    Vb[rb + ni * 16 + col] = f2bf(acc[mi][ni][r]);
            }
    } else {                                         // Q or K: RoPE
        const int isQ = (cb < 2048);
        const int hd = isQ ? (cb >> 6) : ((cb - 2048) >> 6);
        const int nh = isQ ? 32 : 8;
        const float scale = isQ ? 0.125f : 1.0f;
        unsigned short* Out = isQ ? Qb : Kb;
        const float NEG_LN_TH_32 = -0.28782313662425575f;
        const float inv0 = __expf((float)col * NEG_LN_TH_32);
        const float inv1 = __expf((float)(col + 16) * NEG_LN_TH_32);
#pragma unroll
        for (int mi = 0; mi < 8; ++mi)
#pragma unroll
            for (int r = 0; r < 4; ++r) {
                int m = m0 + wm + mi * 16 + quad * 4 + r;
                int b = m >> 11, s = m & 2047;
                float p = (float)pos[m];
                float sn0, cs0, sn1, cs1;
                __sincosf(p * inv0, &sn0, &cs0);
                __sincosf(p * inv1, &sn1, &cs1);
                float a0 = acc[mi][0][r], a1 = acc[mi][1][r];
                float b0 = acc[mi][2][r], b1 = acc[mi][3][r];
                size_t rb = ((size_t)(b * nh + hd) * 2048 + s) * 64;
                Out[rb + col]      = f2bf((a0 * cs0 - b0 * sn0) * scale);
                Out[rb + col + 16] = f2bf((a1 * cs1 - b1 * sn1) * scale);
                Out[rb + col + 32] = f2bf((b0 * cs0 + a0 * sn0) * scale);
                Out[rb + col + 48] = f2bf((b1 * cs1 + a1 * sn1) * scale);
            }
    }
}

// ------------------------------ bf16 GEMM (GEMM2) --------------------------
__global__ __launch_bounds__(256) void gemm_bf16_nt(
    const unsigned short* __restrict__ A, const unsigned short* __restrict__ Bt,
    float* __restrict__ C, int K, int ldc) {
    __shared__ unsigned short As[128 * 64];
    __shared__ unsigned short Bs[128 * 64];
    const int tid = threadIdx.x;
    const int wave = tid >> 6, lane = tid & 63;
    const int col = lane & 15, quad = lane >> 4;
    // XCD-rect swizzle: grid (16,32) -> 8 XCDs x (8x8) rectangles.
    const int lin = blockIdx.y * 16 + blockIdx.x;
    const int xcd = lin & 7, t6 = lin >> 3;          // t6: 0..63
    const int bx = (xcd & 1) * 8 + (t6 & 7);         // 0..15
    const int by = (xcd >> 1) * 8 + (t6 >> 3);       // 0..31
    const int m0 = by * 128, n0 = bx * 128;
    const int wm = (wave >> 1) * 64, wn = (wave & 1) * 64;

    const int lrow = lane >> 3;
    const int gch = (lane & 7) ^ lrow;
    const unsigned short* Ag = A + (size_t)(m0 + wave * 32 + lrow) * K + gch * 8;
    const unsigned short* Bg = Bt + (size_t)(n0 + wave * 32 + lrow) * K + gch * 8;
    unsigned short* AsW = As + wave * 2048;
    unsigned short* BsW = Bs + wave * 2048;

    f32x4 acc[4][4] = {};

    for (int k0 = 0; k0 < K; k0 += 64) {
#pragma unroll
        for (int i = 0; i < 4; ++i) {
            __builtin_amdgcn_global_load_lds(
                (const __attribute__((address_space(1))) void*)(Ag + (size_t)i * 8 * K + k0),
                (__attribute__((address_space(3))) void*)(AsW + i * 512), 16, 0, 0);
            __builtin_amdgcn_global_load_lds(
                (const __attribute__((address_space(1))) void*)(Bg + (size_t)i * 8 * K + k0),
                (__attribute__((address_space(3))) void*)(BsW + i * 512), 16, 0, 0);
        }
        __syncthreads();
#pragma unroll
        for (int ks = 0; ks < 2; ++ks) {
            const int slot = ((ks << 2) + quad) ^ (col & 7);
            s16x8 af[4], bf[4];
#pragma unroll
            for (int mi = 0; mi < 4; ++mi)
                af[mi] = *(const s16x8*)&As[(wm + mi * 16 + col) * 64 + slot * 8];
#pragma unroll
            for (int ni = 0; ni < 4; ++ni)
                bf[ni] = *(const s16x8*)&Bs[(wn + ni * 16 + col) * 64 + slot * 8];
#pragma unroll
            for (int mi = 0; mi < 4; ++mi)
#pragma unroll
                for (int ni = 0; ni < 4; ++ni)
                    acc[mi][ni] = __builtin_amdgcn_mfma_f32_16x16x32_bf16(
                        af[mi], bf[ni], acc[mi][ni], 0, 0, 0);
        }
        __syncthreads();
    }
#pragma unroll
    for (int mi = 0; mi < 4; ++mi)
#pragma unroll
        for (int ni = 0; ni < 4; ++ni)
#pragma unroll
            for (int r = 0; r < 4; ++r) {
                int m = m0 + wm + mi * 16 + quad * 4 + r;
                int n = n0 + wn + ni * 16 + col;
                C[(size_t)m * ldc + n] = acc[mi][ni][r];
            }
}

// ------------------------------ V transpose --------------------------------
__global__ __launch_bounds__(256) void transpose_v(
    const unsigned short* __restrict__ Vb, unsigned short* __restrict__ Vt) {
    __shared__ unsigned short t[64 * 66];
    const int bh = blockIdx.x >> 5, st = blockIdx.x & 31;
    const unsigned short* src = Vb + ((size_t)bh * 2048 + st * 64) * 64;
    unsigned short* dst = Vt + (size_t)bh * 64 * 2048 + st * 64;
    const int r = threadIdx.x >> 2, c = (threadIdx.x & 3) * 16;
    s16x8 v0 = *(const s16x8*)&src[r * 64 + c];
    s16x8 v1 = *(const s16x8*)&src[r * 64 + c + 8];
    unsigned* tw = (unsigned*)&t[r * 66 + c];
#pragma unroll
    for (int q2 = 0; q2 < 4; ++q2) tw[q2] = ((unsigned*)&v0)[q2];
#pragma unroll
    for (int q2 = 0; q2 < 4; ++q2) tw[4 + q2] = ((unsigned*)&v1)[q2];
    __syncthreads();
    const int d = threadIdx.x >> 2, sc2 = (threadIdx.x & 3) * 16;
    unsigned short outv[16];
#pragma unroll
    for (int jj = 0; jj < 16; ++jj) outv[jj] = t[(sc2 + jj) * 66 + d];
    *(s16x8*)&dst[(size_t)d * 2048 + sc2] = *(s16x8*)&outv[0];
    *(s16x8*)&dst[(size_t)d * 2048 + sc2 + 8] = *(s16x8*)&outv[8];
}

// ---------------------------- flash attention v3 ---------------------------
// 1024 blocks x 128 threads (2 waves). Block: strips A=(31-j)*64, B=j*64;
// wave w owns q rows [strip + w*32, +32) of EACH strip (2 q-frags per strip).
__global__ __launch_bounds__(128, 2) void flash_attn(
    const unsigned short* __restrict__ Qb, const unsigned short* __restrict__ Kb,
    const unsigned short* __restrict__ Vt, unsigned short* __restrict__ Ob) {
    __shared__ unsigned short Ks[64 * 64];           // [kv][d]   xor-chunked
    __shared__ unsigned short Vs[64 * 64];           // [d][kv]   xor-chunked
    __shared__ unsigned short PsA[2][32 * 64];       // per-wave P^T->A-layout
    __shared__ unsigned short PsB[2][32 * 64];

    const int tid = threadIdx.x;
    const int wave = tid >> 6, lane = tid & 63;
    const int col = lane & 15, quad = lane >> 4;

    const int id = blockIdx.x;                       // 0..1023
    const int j = ((id & 15) + ((id >> 8) << 2)) & 15;
    const int bh = id >> 4;
    const int b = bh >> 5, h = bh & 31, kvh = h >> 2;
    const int qA0 = (31 - j) * 64, qB0 = j * 64;
    const int qwA = qA0 + wave * 32, qwB = qB0 + wave * 32;

    const unsigned short* Qg  = Qb + ((size_t)(b * 32 + h) * 2048) * 64;
    const unsigned short* Kgb = Kb + ((size_t)(b * 8 + kvh) * 2048) * 64;
    const unsigned short* Vgb = Vt + ((size_t)(b * 8 + kvh) * 64) * 2048;

    const int r8 = lane >> 3, g = (lane & 7) ^ r8;
    const unsigned short* KgL = Kgb + (size_t)(wave * 32 + r8) * 64 + g * 8;
    const unsigned short* VgL = Vgb + (size_t)(wave * 32 + r8) * 2048 + g * 8;
    unsigned short* KsW = Ks + wave * 32 * 64;
    unsigned short* VsW = Vs + wave * 32 * 64;

    const s16x8 onesf = {16256, 16256, 16256, 16256, 16256, 16256, 16256, 16256};

    s16x8 qfA[2][2], qfB[2][2];                      // [q-chunk][ks]
#pragma unroll
    for (int qc = 0; qc < 2; ++qc)
#pragma unroll
        for (int ks = 0; ks < 2; ++ks) {
            qfA[qc][ks] = *(const s16x8*)&Qg[(size_t)(qwA + qc * 16 + col) * 64 + ks * 32 + quad * 8];
            qfB[qc][ks] = *(const s16x8*)&Qg[(size_t)(qwB + qc * 16 + col) * 64 + ks * 32 + quad * 8];
        }

    f32x4 aoA[2][4] = {}, aoB[2][4] = {};            // [q-chunk][d-chunk]
    f32x4 alA[2] = {}, alB[2] = {};

    for (int kv0 = 0; kv0 <= qA0; kv0 += 64) {
#pragma unroll
        for (int i = 0; i < 4; ++i) {                // stage K,V (8 KB each)
            __builtin_amdgcn_global_load_lds(
                (const __attribute__((address_space(1))) void*)(KgL + (size_t)(kv0 + i * 8) * 64),
                (__attribute__((address_space(3))) void*)(KsW + i * 512), 16, 0, 0);
            __builtin_amdgcn_global_load_lds(
                (const __attribute__((address_space(1))) void*)(VgL + kv0 + (size_t)i * 8 * 2048),
                (__attribute__((address_space(3))) void*)(VsW + i * 512), 16, 0, 0);
        }
        __syncthreads();
        const bool doB = (kv0 <= qB0);
        // ---- QK^T (S^T), exp, pack --------------------------------------
#pragma unroll
        for (int mi = 0; mi < 4; ++mi) {
            const int s0 = quad ^ (col & 7);
            const int s1 = (4 + quad) ^ (col & 7);
            s16x8 kf0 = *(const s16x8*)&Ks[(mi * 16 + col) * 64 + s0 * 8];
            s16x8 kf1 = *(const s16x8*)&Ks[(mi * 16 + col) * 64 + s1 * 8];
            const int chl = (mi * 2 + (quad >> 1)) ^ (col & 7);
#pragma unroll
            for (int qc = 0; qc < 2; ++qc) {
                f32x4 sc = {};
                sc = __builtin_amdgcn_mfma_f32_16x16x32_bf16(kf0, qfA[qc][0], sc, 0, 0, 0);
                sc = __builtin_amdgcn_mfma_f32_16x16x32_bf16(kf1, qfA[qc][1], sc, 0, 0, 0);
                if (kv0 == qA0) {                    // diagonal tile mask
                    int kvb = kv0 + mi * 16 + quad * 4, q = qwA + qc * 16 + col;
#pragma unroll
                    for (int r = 0; r < 4; ++r)
                        if (kvb + r > q) sc[r] = -1e30f;
                }
                unsigned eb[4];
#pragma unroll
                for (int r = 0; r < 4; ++r) eb[r] = __float_as_uint(__expf(sc[r]));
                uint2 pk;
                pk.x = __builtin_amdgcn_perm(eb[1], eb[0], 0x07060302u);
                pk.y = __builtin_amdgcn_perm(eb[3], eb[2], 0x07060302u);
                *(uint2*)&PsA[wave][(qc * 16 + col) * 64 + chl * 8 + (quad & 1) * 4] = pk;
            }
            if (doB) {
#pragma unroll
                for (int qc = 0; qc < 2; ++qc) {
                    f32x4 sc = {};
                    sc = __builtin_amdgcn_mfma_f32_16x16x32_bf16(kf0, qfB[qc][0], sc, 0, 0, 0);
                    sc = __builtin_amdgcn_mfma_f32_16x16x32_bf16(kf1, qfB[qc][1], sc, 0, 0, 0);
                    if (kv0 == qB0) {
                        int kvb = kv0 + mi * 16 + quad * 4, q = qwB + qc * 16 + col;
#pragma unroll
                        for (int r = 0; r < 4; ++r)
                            if (kvb + r > q) sc[r] = -1e30f;
                    }
                    unsigned eb[4];
#pragma unroll
                    for (int r = 0; r < 4; ++r) eb[r] = __float_as_uint(__expf(sc[r]));
                    uint2 pk;
                    pk.x = __builtin_amdgcn_perm(eb[1], eb[0], 0x07060302u);
                    pk.y = __builtin_amdgcn_perm(eb[3], eb[2], 0x07060302u);
                    *(uint2*)&PsB[wave][(qc * 16 + col) * 64 + chl * 8 + (quad & 1) * 4] = pk;
                }
            }
        }
        asm volatile("s_waitcnt lgkmcnt(0)" ::: "memory");
        // ---- O += P @ V ; l += P @ 1 (vf shared across 4 q-frags) --------
#pragma unroll
        for (int ks = 0; ks < 2; ++ks) {
            const int slot = ((ks << 2) + quad) ^ (col & 7);
            s16x8 vf[4];
#pragma unroll
            for (int di = 0; di < 4; ++di)
                vf[di] = *(const s16x8*)&Vs[(di * 16 + col) * 64 + slot * 8];
#pragma unroll
            for (int qc = 0; qc < 2; ++qc) {
                s16x8 pfA = *(const s16x8*)&PsA[wave][(qc * 16 + col) * 64 + slot * 8];
                alA[qc] = __builtin_amdgcn_mfma_f32_16x16x32_bf16(pfA, onesf, alA[qc], 0, 0, 0);
#pragma unroll
                for (int di = 0; di < 4; ++di)
                    aoA[qc][di] = __builtin_amdgcn_mfma_f32_16x16x32_bf16(pfA, vf[di], aoA[qc][di], 0, 0, 0);
            }
            if (doB) {
#pragma unroll
                for (int qc = 0; qc < 2; ++qc) {
                    s16x8 pfB = *(const s16x8*)&PsB[wave][(qc * 16 + col) * 64 + slot * 8];
                    alB[qc] = __builtin_amdgcn_mfma_f32_16x16x32_bf16(pfB, onesf, alB[qc], 0, 0, 0);
#pragma unroll
                    for (int di = 0; di < 4; ++di)
                        aoB[qc][di] = __builtin_amdgcn_mfma_f32_16x16x32_bf16(pfB, vf[di], aoB[qc][di], 0, 0, 0);
                }
            }
        }
        __syncthreads();
    }

    // ---- epilogue ---------------------------------------------------------
#pragma unroll
    for (int qc = 0; qc < 2; ++qc)
#pragma unroll
        for (int r = 0; r < 4; ++r) {
            {
                int qg = qwA + qc * 16 + quad * 4 + r;
                float inv = 1.f / alA[qc][r];
                size_t base = ((size_t)b * 2048 + qg) * 2048 + h * 64;
#pragma unroll
                for (int di = 0; di < 4; ++di)
                    Ob[base + di * 16 + col] = f2bf(aoA[qc][di][r] * inv);
            }
            {
                int qg = qwB + qc * 16 + quad * 4 + r;
                float inv = 1.f / alB[qc][r];
                size_t base = ((size_t)b * 2048 + qg) * 2048 + h * 64;
#pragma unroll
                for (int di = 0; di < 4; ++di)
                    Ob[base + di * 16 + col] = f2bf(aoB[qc][di][r] * inv);
            }
        }
}

// ------------------------------- launcher ----------------------------------
extern "C" void kernel_launch(void* const* d_in, const int* in_sizes, int n_in,
                              void* d_out, int out_size, void* d_ws, size_t ws_size,
                              hipStream_t stream) {
    const float* X  = (const float*)d_in[0];
    const float* Wq = (const float*)d_in[1];
    const float* Wk = (const float*)d_in[2];
    const float* Wv = (const float*)d_in[3];
    const float* Wo = (const float*)d_in[4];
    const int* pos  = (const int*)d_in[6];
    float* out = (float*)d_out;

    char* ws = (char*)d_ws;
    unsigned short* Xb    = (unsigned short*)(ws + 0);          // 16 MB (reused as Attn)
    unsigned short* Wqkvt = (unsigned short*)(ws + 16777216);   // 12 MB
    unsigned short* Wot   = (unsigned short*)(ws + 29360128);   // 8 MB
    unsigned short* Qb    = (unsigned short*)(ws + 37748736);   // 16 MB
    unsigned short* Kb    = (unsigned short*)(ws + 54525952);   // 4 MB
    unsigned short* Vb    = (unsigned short*)(ws + 58720256);   // 4 MB
    unsigned short* Vt    = (unsigned short*)(ws + 62914560);   // 4 MB
    unsigned short* Attn  = Xb;                                 // alias

    prep<<<18432, 256, 0, stream>>>(X, Wq, Wk, Wv, Wo, Xb, Wqkvt, Wot);
    gemm_qkv_rope<<<dim3(12, 16), 512, 0, stream>>>(Xb, Wqkvt, pos, Qb, Kb, Vb);
    transpose_v<<<512, 256, 0, stream>>>(Vb, Vt);
    flash_attn<<<1024, 128, 0, stream>>>(Qb, Kb, Vt, Attn);
    gemm_bf16_nt<<<dim3(16, 32), 256, 0, stream>>>(Attn, Wot, out, 2048, 2048);
}